// Round 1
// baseline (58231.812 us; speedup 1.0000x reference)
//
#include <hip/hip_runtime.h>
#include <math.h>

#define B 64
#define TIN 128
#define N_IN 256
#define M 1024
#define O_DIM 512
#define LM 2048
#define TDEC 64

// ---------------------------------------------------------------------------
// Transpose X (B,TIN,N) -> Xt (TIN,B,N)
// ---------------------------------------------------------------------------
__global__ __launch_bounds__(256) void transpose_X(const float* __restrict__ X,
                                                   float* __restrict__ Xt) {
    int idx = blockIdx.x * 256 + threadIdx.x;   // = t*(B*N) + b*N + n
    int n = idx & (N_IN - 1);
    int b = (idx >> 8) & (B - 1);
    int t = idx >> 14;
    Xt[idx] = X[(b * TIN + t) * N_IN + n];
}

// ---------------------------------------------------------------------------
// C[r][c] = sum_k A[r][k] * W[c][k] + bias[c]
// A: (rows x K) row-major stride lda; W: (cols x K) row-major stride ldw.
// grid.x * 64 == cols, grid.y * 64 == rows (all dims multiples of 64/16).
// ---------------------------------------------------------------------------
__global__ __launch_bounds__(256) void gemm_bias(const float* __restrict__ A, int lda,
                                                 const float* __restrict__ W, int ldw,
                                                 const float* __restrict__ bias,
                                                 float* __restrict__ C, int ldc,
                                                 int K) {
    __shared__ float As[64][17];
    __shared__ float Ws[64][17];
    const int tx = threadIdx.x, ty = threadIdx.y;
    const int tid = ty * 16 + tx;
    const int row0 = blockIdx.y * 64;
    const int col0 = blockIdx.x * 64;
    float acc[4][4] = {};
    for (int k0 = 0; k0 < K; k0 += 16) {
        #pragma unroll
        for (int i = 0; i < 4; i++) {
            int idx = tid + i * 256;      // 0..1023
            int r = idx >> 4, c = idx & 15;
            As[r][c] = A[(row0 + r) * lda + k0 + c];
            Ws[r][c] = W[(col0 + r) * ldw + k0 + c];
        }
        __syncthreads();
        #pragma unroll
        for (int kk = 0; kk < 16; kk++) {
            float a[4], bb[4];
            #pragma unroll
            for (int i = 0; i < 4; i++) a[i] = As[ty * 4 + i][kk];
            #pragma unroll
            for (int j = 0; j < 4; j++) bb[j] = Ws[tx * 4 + j][kk];
            #pragma unroll
            for (int i = 0; i < 4; i++)
                #pragma unroll
                for (int j = 0; j < 4; j++) acc[i][j] += a[i] * bb[j];
        }
        __syncthreads();
    }
    #pragma unroll
    for (int i = 0; i < 4; i++) {
        int r = row0 + ty * 4 + i;
        #pragma unroll
        for (int j = 0; j < 4; j++) {
            int c = col0 + tx * 4 + j;
            C[r * ldc + c] = acc[i][j] + bias[c];
        }
    }
}

// ---------------------------------------------------------------------------
// GRU pointwise: h' = (1-z)*n + z*h ; writes h in place, optional seq_out copy.
// gi/gh rows: [r | z | n] blocks of M. grid*block == B*M.
// ---------------------------------------------------------------------------
__global__ __launch_bounds__(256) void gru_pw(const float* __restrict__ gi,
                                              const float* __restrict__ gh,
                                              float* __restrict__ h,
                                              float* __restrict__ seq_out) {
    int idx = blockIdx.x * 256 + threadIdx.x;    // b*M + m
    int b = idx >> 10, m = idx & (M - 1);
    const float* gir = gi + b * 3 * M;
    const float* ghr = gh + b * 3 * M;
    float r = 1.f / (1.f + expf(-(gir[m] + ghr[m])));
    float z = 1.f / (1.f + expf(-(gir[M + m] + ghr[M + m])));
    float n = tanhf(gir[2 * M + m] + r * ghr[2 * M + m]);
    float hv = (1.f - z) * n + z * h[idx];
    h[idx] = hv;
    if (seq_out) seq_out[idx] = hv;
}

// ---------------------------------------------------------------------------
// LayerNorm + exact GELU over rows of length LM, in place. one block per row.
// ---------------------------------------------------------------------------
__global__ __launch_bounds__(256) void ln_gelu(float* __restrict__ z,
                                               const float* __restrict__ g,
                                               const float* __restrict__ bt) {
    __shared__ float red1[4], red2[4];
    int b = blockIdx.x, t = threadIdx.x;
    float* row = z + b * LM;
    float s = 0.f, ss = 0.f;
    for (int i = t; i < LM; i += 256) { float v = row[i]; s += v; ss += v * v; }
    #pragma unroll
    for (int off = 32; off > 0; off >>= 1) {
        s += __shfl_down(s, off, 64);
        ss += __shfl_down(ss, off, 64);
    }
    if ((t & 63) == 0) { red1[t >> 6] = s; red2[t >> 6] = ss; }
    __syncthreads();
    float S = red1[0] + red1[1] + red1[2] + red1[3];
    float SS = red2[0] + red2[1] + red2[2] + red2[3];
    float mu = S * (1.f / LM);
    float var = SS * (1.f / LM) - mu * mu;
    float inv = rsqrtf(var + 1e-5f);
    for (int i = t; i < LM; i += 256) {
        float v = (row[i] - mu) * inv * g[i] + bt[i];
        row[i] = 0.5f * v * (1.f + erff(v * 0.70710678118654752f));
    }
}

// ---------------------------------------------------------------------------
// Row softmax over O_DIM=512 logits (row stride ldl) -> y (compact B x O).
// ---------------------------------------------------------------------------
__global__ __launch_bounds__(256) void softmax_row(const float* __restrict__ logits,
                                                   int ldl, float* __restrict__ y) {
    __shared__ float redm[4], reds[4];
    int b = blockIdx.x, t = threadIdx.x;
    const float* row = logits + b * ldl;
    float v0 = row[t], v1 = row[t + 256];
    float mx = fmaxf(v0, v1);
    #pragma unroll
    for (int off = 32; off > 0; off >>= 1) mx = fmaxf(mx, __shfl_down(mx, off, 64));
    if ((t & 63) == 0) redm[t >> 6] = mx;
    __syncthreads();
    mx = fmaxf(fmaxf(redm[0], redm[1]), fmaxf(redm[2], redm[3]));
    float e0 = expf(v0 - mx), e1 = expf(v1 - mx);
    float s = e0 + e1;
    #pragma unroll
    for (int off = 32; off > 0; off >>= 1) s += __shfl_down(s, off, 64);
    if ((t & 63) == 0) reds[t >> 6] = s;
    __syncthreads();
    s = reds[0] + reds[1] + reds[2] + reds[3];
    float inv = 1.f / s;
    y[b * O_DIM + t] = e0 * inv;
    y[b * O_DIM + t + 256] = e1 * inv;
}

extern "C" void kernel_launch(void* const* d_in, const int* in_sizes, int n_in,
                              void* d_out, int out_size, void* d_ws, size_t ws_size,
                              hipStream_t stream) {
    const float* X        = (const float*)d_in[0];
    const float* Y0       = (const float*)d_in[1];
    const float* enc_Wih0 = (const float*)d_in[2];
    const float* enc_Whh0 = (const float*)d_in[3];
    const float* enc_bih0 = (const float*)d_in[4];
    const float* enc_bhh0 = (const float*)d_in[5];
    const float* enc_Wih1 = (const float*)d_in[6];
    const float* enc_Whh1 = (const float*)d_in[7];
    const float* enc_bih1 = (const float*)d_in[8];
    const float* enc_bhh1 = (const float*)d_in[9];
    const float* dec_Wih0 = (const float*)d_in[10];
    const float* dec_Whh0 = (const float*)d_in[11];
    const float* dec_bih0 = (const float*)d_in[12];
    const float* dec_bhh0 = (const float*)d_in[13];
    const float* dec_Wih1 = (const float*)d_in[14];
    const float* dec_Whh1 = (const float*)d_in[15];
    const float* dec_bih1 = (const float*)d_in[16];
    const float* dec_bhh1 = (const float*)d_in[17];
    const float* fc1_w    = (const float*)d_in[18];
    const float* fc1_b    = (const float*)d_in[19];
    const float* ln_g     = (const float*)d_in[20];
    const float* ln_b     = (const float*)d_in[21];
    const float* fc2_w    = (const float*)d_in[22];
    const float* fc2_b    = (const float*)d_in[23];
    float* out = (float*)d_out;

    // workspace carve-up (floats)
    float* ws    = (float*)d_ws;
    float* Xt    = ws;                                  // TIN*B*N_IN    = 2,097,152
    float* seqA  = Xt   + (size_t)TIN * B * N_IN;       // TIN*B*M       = 8,388,608
    float* gi_ch = seqA + (size_t)TIN * B * M;          // 32*B*3M       = 6,291,456
    float* ghB   = gi_ch + (size_t)32 * B * 3 * M;      // B*3M
    float* giB   = ghB  + (size_t)B * 3 * M;            // B*3M
    float* h0    = giB  + (size_t)B * 3 * M;            // B*M
    float* h1    = h0   + (size_t)B * M;                // B*M
    float* yb    = h1   + (size_t)B * M;                // B*O
    float* zb    = yb   + (size_t)B * O_DIM;            // B*LM

    dim3 blk(16, 16);
    const int CH = 32;  // encoder gi chunking (ws economy)

    transpose_X<<<(TIN * B * N_IN) / 256, 256, 0, stream>>>(X, Xt);
    hipMemsetAsync(h0, 0, (size_t)B * M * sizeof(float), stream);
    hipMemsetAsync(h1, 0, (size_t)B * M * sizeof(float), stream);

    // -------------------- encoder --------------------
    for (int layer = 0; layer < 2; layer++) {
        const float* Wih = layer ? enc_Wih1 : enc_Wih0;
        const float* Whh = layer ? enc_Whh1 : enc_Whh0;
        const float* bih = layer ? enc_bih1 : enc_bih0;
        const float* bhh = layer ? enc_bhh1 : enc_bhh0;
        const float* inseq = layer ? seqA : Xt;
        const int Kin = layer ? M : N_IN;
        float* h = layer ? h1 : h0;
        for (int c = 0; c < TIN / CH; c++) {
            // batched gi for CH timesteps: (CH*B) x 3M
            gemm_bias<<<dim3(3 * M / 64, CH * B / 64), blk, 0, stream>>>(
                inseq + (size_t)c * CH * B * Kin, Kin, Wih, Kin, bih,
                gi_ch, 3 * M, Kin);
            for (int tt = 0; tt < CH; tt++) {
                gemm_bias<<<dim3(3 * M / 64, 1), blk, 0, stream>>>(
                    h, M, Whh, M, bhh, ghB, 3 * M, M);
                float* so = (layer == 0) ? (seqA + (size_t)(c * CH + tt) * B * M)
                                         : nullptr;
                gru_pw<<<(B * M) / 256, 256, 0, stream>>>(
                    gi_ch + (size_t)tt * B * 3 * M, ghB, h, so);
            }
        }
    }

    // -------------------- decoder --------------------
    hipMemcpyAsync(yb, Y0, (size_t)B * O_DIM * sizeof(float),
                   hipMemcpyDeviceToDevice, stream);
    for (int t = 0; t < TDEC; t++) {
        // GRU layer 0: input y (O_DIM)
        gemm_bias<<<dim3(48, 1), blk, 0, stream>>>(yb, O_DIM, dec_Wih0, O_DIM,
                                                   dec_bih0, giB, 3 * M, O_DIM);
        gemm_bias<<<dim3(48, 1), blk, 0, stream>>>(h0, M, dec_Whh0, M,
                                                   dec_bhh0, ghB, 3 * M, M);
        gru_pw<<<(B * M) / 256, 256, 0, stream>>>(giB, ghB, h0, nullptr);
        // GRU layer 1: input h0 (M)
        gemm_bias<<<dim3(48, 1), blk, 0, stream>>>(h0, M, dec_Wih1, M,
                                                   dec_bih1, giB, 3 * M, M);
        gemm_bias<<<dim3(48, 1), blk, 0, stream>>>(h1, M, dec_Whh1, M,
                                                   dec_bhh1, ghB, 3 * M, M);
        gru_pw<<<(B * M) / 256, 256, 0, stream>>>(giB, ghB, h1, nullptr);
        // head: fc1 -> LN -> GELU -> fc2(logits into d_out) -> softmax -> y
        gemm_bias<<<dim3(LM / 64, 1), blk, 0, stream>>>(h1, M, fc1_w, M, fc1_b,
                                                        zb, LM, M);
        ln_gelu<<<B, 256, 0, stream>>>(zb, ln_g, ln_b);
        gemm_bias<<<dim3(O_DIM / 64, 1), blk, 0, stream>>>(
            zb, LM, fc2_w, LM, fc2_b, out + t * O_DIM, TDEC * O_DIM, LM);
        softmax_row<<<B, 256, 0, stream>>>(out + t * O_DIM, TDEC * O_DIM, yb);
    }
}

// Round 2
// 9349.720 us; speedup vs baseline: 6.2282x; 6.2282x over previous
//
#include <hip/hip_runtime.h>
#include <math.h>

#define B 64
#define TIN 128
#define N_IN 256
#define M 1024
#define O_DIM 512
#define LM 2048
#define TDEC 64
#define M3 3072
#define CH 8   // encoder gi timestep chunk

typedef short bf16x8 __attribute__((ext_vector_type(8)));
typedef float floatx4 __attribute__((ext_vector_type(4)));

__device__ __forceinline__ unsigned short f2bf(float f) {
    unsigned int u = __float_as_uint(f);
    u += 0x7FFFu + ((u >> 16) & 1u);      // round-to-nearest-even
    return (unsigned short)(u >> 16);
}
__device__ __forceinline__ float sigm(float x) { return 1.f / (1.f + expf(-x)); }

// ---------------------------------------------------------------------------
// fp32 -> bf16 cast (weights, Y0)
// ---------------------------------------------------------------------------
__global__ __launch_bounds__(256) void cast_bf(const float* __restrict__ in,
                                               short* __restrict__ out, int n) {
    int i = blockIdx.x * 256 + threadIdx.x;
    if (i < n) out[i] = (short)f2bf(in[i]);
}

// ---------------------------------------------------------------------------
// X (B,TIN,N) fp32 -> Xt (TIN,B,N) bf16
// ---------------------------------------------------------------------------
__global__ __launch_bounds__(256) void transpose_X_bf(const float* __restrict__ X,
                                                      short* __restrict__ Xt) {
    int idx = blockIdx.x * 256 + threadIdx.x;   // t*(B*N) + b*N + n
    int n = idx & (N_IN - 1);
    int b = (idx >> 8) & (B - 1);
    int t = idx >> 14;
    Xt[idx] = (short)f2bf(X[(b * TIN + t) * N_IN + n]);
}

// ---------------------------------------------------------------------------
// Plain MFMA GEMM: C[r][c] = sum_k A[r][k]*W[c][k] + bias[c]
// A (rows x K) bf16, W (cols x K) bf16, C fp32. grid=(cols/16, rows/64),
// block=256 (4 waves, one 16-row tile each).
// ---------------------------------------------------------------------------
__global__ __launch_bounds__(256) void mfma_gemm_bias(
    const short* __restrict__ A, int lda,
    const short* __restrict__ W, int ldw,
    const float* __restrict__ bias,
    float* __restrict__ C, int ldc, int K) {
    int wave = threadIdx.x >> 6;
    int lane = threadIdx.x & 63;
    int r0 = blockIdx.y * 64 + wave * 16;
    int c0 = blockIdx.x * 16;
    int lrow = lane & 15;
    int ko8 = (lane >> 4) * 8;
    const short* ap = A + (size_t)(r0 + lrow) * lda + ko8;
    const short* wp = W + (size_t)(c0 + lrow) * ldw + ko8;
    floatx4 acc = {0.f, 0.f, 0.f, 0.f};
    #pragma unroll 4
    for (int k = 0; k < K; k += 32) {
        bf16x8 a = *(const bf16x8*)(ap + k);
        bf16x8 b = *(const bf16x8*)(wp + k);
        acc = __builtin_amdgcn_mfma_f32_16x16x32_bf16(a, b, acc, 0, 0, 0);
    }
    int col = c0 + lrow;
    float bv = bias[col];
    int rbase = r0 + (lane >> 4) * 4;
    #pragma unroll
    for (int i = 0; i < 4; i++)
        C[(size_t)(rbase + i) * ldc + col] = acc[i] + bv;
}

// ---------------------------------------------------------------------------
// Encoder GRU step, fully fused: gh = h@Whh.T (MFMA) + pointwise.
// gi (fp32, incl. bih) precomputed batched. grid=(M/16, B/16), block=64.
// h_f fp32 master state (in/out, element-owned per block -> in-place safe);
// h bf16 mirror is ping-ponged (h_in_bf -> h_out_bf).
// ---------------------------------------------------------------------------
__global__ __launch_bounds__(64) void gru_step_enc(
    const short* __restrict__ h_in_bf, const short* __restrict__ Whh,
    const float* __restrict__ gi, const float* __restrict__ bhh,
    float* __restrict__ h_f, short* __restrict__ h_out_bf,
    short* __restrict__ seq_out_bf) {
    int lane = threadIdx.x;
    int m0 = blockIdx.x * 16;
    int r0 = blockIdx.y * 16;
    int lrow = lane & 15;
    int ko8 = (lane >> 4) * 8;
    const short* ap = h_in_bf + (size_t)(r0 + lrow) * M + ko8;
    const short* wr = Whh + (size_t)(m0 + lrow) * M + ko8;
    const short* wz = wr + (size_t)M * M;
    const short* wn = wr + (size_t)2 * M * M;
    floatx4 ar = {0.f, 0.f, 0.f, 0.f};
    floatx4 az = {0.f, 0.f, 0.f, 0.f};
    floatx4 ahn = {0.f, 0.f, 0.f, 0.f};
    #pragma unroll 4
    for (int k = 0; k < M; k += 32) {
        bf16x8 a = *(const bf16x8*)(ap + k);
        ar = __builtin_amdgcn_mfma_f32_16x16x32_bf16(a, *(const bf16x8*)(wr + k), ar, 0, 0, 0);
        az = __builtin_amdgcn_mfma_f32_16x16x32_bf16(a, *(const bf16x8*)(wz + k), az, 0, 0, 0);
        ahn = __builtin_amdgcn_mfma_f32_16x16x32_bf16(a, *(const bf16x8*)(wn + k), ahn, 0, 0, 0);
    }
    int m = m0 + lrow;
    float b_r = bhh[m], b_z = bhh[M + m], b_n = bhh[2 * M + m];
    int rbase = r0 + (lane >> 4) * 4;
    #pragma unroll
    for (int i = 0; i < 4; i++) {
        int b = rbase + i;
        const float* gir = gi + (size_t)b * M3;
        float r = sigm(gir[m] + ar[i] + b_r);
        float z = sigm(gir[M + m] + az[i] + b_z);
        float n = tanhf(gir[2 * M + m] + r * (ahn[i] + b_n));
        size_t hi = (size_t)b * M + m;
        float hv = (1.f - z) * n + z * h_f[hi];
        h_f[hi] = hv;
        short hb = (short)f2bf(hv);
        h_out_bf[hi] = hb;
        if (seq_out_bf) seq_out_bf[hi] = hb;
    }
}

// ---------------------------------------------------------------------------
// Decoder GRU step, fully fused: gi = x@Wih.T, gh = h@Whh.T, pointwise.
// r/z gates accumulate gi+gh jointly; n gate kept split (needs i_n + r*h_n).
// grid=(M/16, B/16), block=64.
// ---------------------------------------------------------------------------
__global__ __launch_bounds__(64) void gru_step_dec(
    const short* __restrict__ x_bf, int Kx,
    const short* __restrict__ Wih,
    const short* __restrict__ h_in_bf, const short* __restrict__ Whh,
    const float* __restrict__ bih, const float* __restrict__ bhh,
    float* __restrict__ h_f, short* __restrict__ h_out_bf) {
    int lane = threadIdx.x;
    int m0 = blockIdx.x * 16;
    int r0 = blockIdx.y * 16;
    int lrow = lane & 15;
    int ko8 = (lane >> 4) * 8;
    floatx4 ar = {0.f, 0.f, 0.f, 0.f};
    floatx4 az = {0.f, 0.f, 0.f, 0.f};
    floatx4 ain = {0.f, 0.f, 0.f, 0.f};
    floatx4 ahn = {0.f, 0.f, 0.f, 0.f};
    {   // input-side: gi
        const short* ap = x_bf + (size_t)(r0 + lrow) * Kx + ko8;
        const short* wr = Wih + (size_t)(m0 + lrow) * Kx + ko8;
        const short* wz = wr + (size_t)M * Kx;
        const short* wn = wr + (size_t)2 * M * Kx;
        #pragma unroll 2
        for (int k = 0; k < Kx; k += 32) {
            bf16x8 a = *(const bf16x8*)(ap + k);
            ar = __builtin_amdgcn_mfma_f32_16x16x32_bf16(a, *(const bf16x8*)(wr + k), ar, 0, 0, 0);
            az = __builtin_amdgcn_mfma_f32_16x16x32_bf16(a, *(const bf16x8*)(wz + k), az, 0, 0, 0);
            ain = __builtin_amdgcn_mfma_f32_16x16x32_bf16(a, *(const bf16x8*)(wn + k), ain, 0, 0, 0);
        }
    }
    {   // hidden-side: gh
        const short* ap = h_in_bf + (size_t)(r0 + lrow) * M + ko8;
        const short* wr = Whh + (size_t)(m0 + lrow) * M + ko8;
        const short* wz = wr + (size_t)M * M;
        const short* wn = wr + (size_t)2 * M * M;
        #pragma unroll 2
        for (int k = 0; k < M; k += 32) {
            bf16x8 a = *(const bf16x8*)(ap + k);
            ar = __builtin_amdgcn_mfma_f32_16x16x32_bf16(a, *(const bf16x8*)(wr + k), ar, 0, 0, 0);
            az = __builtin_amdgcn_mfma_f32_16x16x32_bf16(a, *(const bf16x8*)(wz + k), az, 0, 0, 0);
            ahn = __builtin_amdgcn_mfma_f32_16x16x32_bf16(a, *(const bf16x8*)(wn + k), ahn, 0, 0, 0);
        }
    }
    int m = m0 + lrow;
    float br_i = bih[m], bz_i = bih[M + m], bn_i = bih[2 * M + m];
    float br_h = bhh[m], bz_h = bhh[M + m], bn_h = bhh[2 * M + m];
    int rbase = r0 + (lane >> 4) * 4;
    #pragma unroll
    for (int i = 0; i < 4; i++) {
        int b = rbase + i;
        float r = sigm(ar[i] + br_i + br_h);
        float z = sigm(az[i] + bz_i + bz_h);
        float n = tanhf(ain[i] + bn_i + r * (ahn[i] + bn_h));
        size_t hi = (size_t)b * M + m;
        float hv = (1.f - z) * n + z * h_f[hi];
        h_f[hi] = hv;
        h_out_bf[hi] = (short)f2bf(hv);
    }
}

// ---------------------------------------------------------------------------
// LayerNorm + exact GELU over rows of length LM; reads fp32, writes bf16.
// ---------------------------------------------------------------------------
__global__ __launch_bounds__(256) void ln_gelu(const float* __restrict__ z,
                                               const float* __restrict__ g,
                                               const float* __restrict__ bt,
                                               short* __restrict__ zo) {
    __shared__ float red1[4], red2[4];
    int b = blockIdx.x, t = threadIdx.x;
    const float* row = z + (size_t)b * LM;
    float s = 0.f, ss = 0.f;
    for (int i = t; i < LM; i += 256) { float v = row[i]; s += v; ss += v * v; }
    #pragma unroll
    for (int off = 32; off > 0; off >>= 1) {
        s += __shfl_down(s, off, 64);
        ss += __shfl_down(ss, off, 64);
    }
    if ((t & 63) == 0) { red1[t >> 6] = s; red2[t >> 6] = ss; }
    __syncthreads();
    float S = red1[0] + red1[1] + red1[2] + red1[3];
    float SS = red2[0] + red2[1] + red2[2] + red2[3];
    float mu = S * (1.f / LM);
    float var = SS * (1.f / LM) - mu * mu;
    float inv = rsqrtf(var + 1e-5f);
    for (int i = t; i < LM; i += 256) {
        float v = (row[i] - mu) * inv * g[i] + bt[i];
        float gv = 0.5f * v * (1.f + erff(v * 0.70710678118654752f));
        zo[(size_t)b * LM + i] = (short)f2bf(gv);
    }
}

// ---------------------------------------------------------------------------
// Row softmax over O logits (fp32, stride ldl) -> y bf16 (compact B x O).
// ---------------------------------------------------------------------------
__global__ __launch_bounds__(256) void softmax_row(const float* __restrict__ logits,
                                                   int ldl, short* __restrict__ y) {
    __shared__ float redm[4], reds[4];
    int b = blockIdx.x, t = threadIdx.x;
    const float* row = logits + (size_t)b * ldl;
    float v0 = row[t], v1 = row[t + 256];
    float mx = fmaxf(v0, v1);
    #pragma unroll
    for (int off = 32; off > 0; off >>= 1) mx = fmaxf(mx, __shfl_down(mx, off, 64));
    if ((t & 63) == 0) redm[t >> 6] = mx;
    __syncthreads();
    mx = fmaxf(fmaxf(redm[0], redm[1]), fmaxf(redm[2], redm[3]));
    float e0 = expf(v0 - mx), e1 = expf(v1 - mx);
    float s = e0 + e1;
    #pragma unroll
    for (int off = 32; off > 0; off >>= 1) s += __shfl_down(s, off, 64);
    if ((t & 63) == 0) reds[t >> 6] = s;
    __syncthreads();
    s = reds[0] + reds[1] + reds[2] + reds[3];
    float inv = 1.f / s;
    y[b * O_DIM + t] = (short)f2bf(e0 * inv);
    y[b * O_DIM + t + 256] = (short)f2bf(e1 * inv);
}

extern "C" void kernel_launch(void* const* d_in, const int* in_sizes, int n_in,
                              void* d_out, int out_size, void* d_ws, size_t ws_size,
                              hipStream_t stream) {
    const float* X        = (const float*)d_in[0];
    const float* Y0       = (const float*)d_in[1];
    const float* enc_Wih0 = (const float*)d_in[2];
    const float* enc_Whh0 = (const float*)d_in[3];
    const float* enc_bih0 = (const float*)d_in[4];
    const float* enc_bhh0 = (const float*)d_in[5];
    const float* enc_Wih1 = (const float*)d_in[6];
    const float* enc_Whh1 = (const float*)d_in[7];
    const float* enc_bih1 = (const float*)d_in[8];
    const float* enc_bhh1 = (const float*)d_in[9];
    const float* dec_Wih0 = (const float*)d_in[10];
    const float* dec_Whh0 = (const float*)d_in[11];
    const float* dec_bih0 = (const float*)d_in[12];
    const float* dec_bhh0 = (const float*)d_in[13];
    const float* dec_Wih1 = (const float*)d_in[14];
    const float* dec_Whh1 = (const float*)d_in[15];
    const float* dec_bih1 = (const float*)d_in[16];
    const float* dec_bhh1 = (const float*)d_in[17];
    const float* fc1_w    = (const float*)d_in[18];
    const float* fc1_b    = (const float*)d_in[19];
    const float* ln_g     = (const float*)d_in[20];
    const float* ln_b     = (const float*)d_in[21];
    const float* fc2_w    = (const float*)d_in[22];
    const float* fc2_b    = (const float*)d_in[23];
    float* out = (float*)d_out;

    // ---- workspace carve-up ----
    char* p = (char*)d_ws;
    auto carve = [&](size_t bytes) {
        void* r = p;
        p += (bytes + 255) & ~(size_t)255;
        return r;
    };
    short* Xt    = (short*)carve((size_t)TIN * B * N_IN * 2);   // 4 MB
    short* seqA  = (short*)carve((size_t)TIN * B * M * 2);      // 16 MB
    float* gi_ch = (float*)carve((size_t)CH * B * M3 * 4);      // 6 MB
    short* we_ih0 = (short*)carve((size_t)M3 * N_IN * 2);
    short* we_hh0 = (short*)carve((size_t)M3 * M * 2);
    short* we_ih1 = (short*)carve((size_t)M3 * M * 2);
    short* we_hh1 = (short*)carve((size_t)M3 * M * 2);
    short* wd_ih0 = (short*)carve((size_t)M3 * O_DIM * 2);
    short* wd_hh0 = (short*)carve((size_t)M3 * M * 2);
    short* wd_ih1 = (short*)carve((size_t)M3 * M * 2);
    short* wd_hh1 = (short*)carve((size_t)M3 * M * 2);
    short* wfc1   = (short*)carve((size_t)LM * M * 2);
    short* wfc2   = (short*)carve((size_t)O_DIM * LM * 2);
    float* h0f = (float*)carve((size_t)B * M * 4);
    float* h1f = (float*)carve((size_t)B * M * 4);
    short* h0b = (short*)carve((size_t)2 * B * M * 2);   // ping-pong
    short* h1b = (short*)carve((size_t)2 * B * M * 2);
    short* yb  = (short*)carve((size_t)B * O_DIM * 2);
    float* zb  = (float*)carve((size_t)B * LM * 4);
    short* zbb = (short*)carve((size_t)B * LM * 2);

    auto cast = [&](const float* src, short* dst, int n) {
        cast_bf<<<(n + 255) / 256, 256, 0, stream>>>(src, dst, n);
    };
    cast(enc_Wih0, we_ih0, M3 * N_IN);
    cast(enc_Whh0, we_hh0, M3 * M);
    cast(enc_Wih1, we_ih1, M3 * M);
    cast(enc_Whh1, we_hh1, M3 * M);
    cast(dec_Wih0, wd_ih0, M3 * O_DIM);
    cast(dec_Whh0, wd_hh0, M3 * M);
    cast(dec_Wih1, wd_ih1, M3 * M);
    cast(dec_Whh1, wd_hh1, M3 * M);
    cast(fc1_w, wfc1, LM * M);
    cast(fc2_w, wfc2, O_DIM * LM);
    cast(Y0, yb, B * O_DIM);
    transpose_X_bf<<<(TIN * B * N_IN) / 256, 256, 0, stream>>>(X, Xt);

    hipMemsetAsync(h0f, 0, (size_t)B * M * 4, stream);
    hipMemsetAsync(h1f, 0, (size_t)B * M * 4, stream);
    hipMemsetAsync(h0b, 0, (size_t)B * M * 2, stream);   // parity-0 buffer
    hipMemsetAsync(h1b, 0, (size_t)B * M * 2, stream);

    dim3 gruGrid(M / 16, B / 16);     // 64 x 4 = 256 blocks

    // -------------------- encoder --------------------
    for (int layer = 0; layer < 2; layer++) {
        const short* Wih = layer ? we_ih1 : we_ih0;
        const short* Whh = layer ? we_hh1 : we_hh0;
        const float* bih = layer ? enc_bih1 : enc_bih0;
        const float* bhh = layer ? enc_bhh1 : enc_bhh0;
        const short* inseq = layer ? seqA : Xt;
        const int Kin = layer ? M : N_IN;
        float* hf = layer ? h1f : h0f;
        short* hb = layer ? h1b : h0b;
        for (int c = 0; c < TIN / CH; c++) {
            mfma_gemm_bias<<<dim3(M3 / 16, CH * B / 64), 256, 0, stream>>>(
                inseq + (size_t)c * CH * B * Kin, Kin, Wih, Kin, bih,
                gi_ch, M3, Kin);
            for (int tt = 0; tt < CH; tt++) {
                int t = c * CH + tt;
                int pin = t & 1, pout = pin ^ 1;
                short* so = (layer == 0) ? (seqA + (size_t)t * B * M) : nullptr;
                gru_step_enc<<<gruGrid, 64, 0, stream>>>(
                    hb + (size_t)pin * B * M, Whh,
                    gi_ch + (size_t)tt * B * M3, bhh,
                    hf, hb + (size_t)pout * B * M, so);
            }
        }
    }
    // after 128 steps the live bf16 state is at parity 0 for both layers.

    // -------------------- decoder --------------------
    for (int t = 0; t < TDEC; t++) {
        int pin = t & 1, pout = pin ^ 1;
        gru_step_dec<<<gruGrid, 64, 0, stream>>>(
            yb, O_DIM, wd_ih0,
            h0b + (size_t)pin * B * M, wd_hh0,
            dec_bih0, dec_bhh0, h0f, h0b + (size_t)pout * B * M);
        gru_step_dec<<<gruGrid, 64, 0, stream>>>(
            h0b + (size_t)pout * B * M, M, wd_ih1,
            h1b + (size_t)pin * B * M, wd_hh1,
            dec_bih1, dec_bhh1, h1f, h1b + (size_t)pout * B * M);
        mfma_gemm_bias<<<dim3(LM / 16, 1), 256, 0, stream>>>(
            h1b + (size_t)pout * B * M, M, wfc1, M, fc1_b, zb, LM, M);
        ln_gelu<<<B, 256, 0, stream>>>(zb, ln_g, ln_b, zbb);
        mfma_gemm_bias<<<dim3(O_DIM / 16, 1), 256, 0, stream>>>(
            zbb, LM, wfc2, LM, fc2_b, out + (size_t)t * O_DIM, TDEC * O_DIM, LM);
        softmax_row<<<B, 256, 0, stream>>>(out + (size_t)t * O_DIM,
                                           TDEC * O_DIM, yb);
    }
}

// Round 3
// 5547.302 us; speedup vs baseline: 10.4973x; 1.6855x over previous
//
#include <hip/hip_runtime.h>
#include <math.h>

#define B 64
#define TIN 128
#define N_IN 256
#define M 1024
#define O_DIM 512
#define LM 2048
#define TDEC 64
#define M3 3072
#define CH 8   // encoder gi timestep chunk

typedef short bf16x8 __attribute__((ext_vector_type(8)));
typedef float floatx4 __attribute__((ext_vector_type(4)));

__device__ __forceinline__ unsigned short f2bf(float f) {
    unsigned int u = __float_as_uint(f);
    u += 0x7FFFu + ((u >> 16) & 1u);      // round-to-nearest-even
    return (unsigned short)(u >> 16);
}
__device__ __forceinline__ float sigm(float x) { return 1.f / (1.f + expf(-x)); }

// ---------------------------------------------------------------------------
// fp32 -> bf16 cast (weights, Y0)
// ---------------------------------------------------------------------------
__global__ __launch_bounds__(256) void cast_bf(const float* __restrict__ in,
                                               short* __restrict__ out, int n) {
    int i = blockIdx.x * 256 + threadIdx.x;
    if (i < n) out[i] = (short)f2bf(in[i]);
}

// ---------------------------------------------------------------------------
// X (B,TIN,N) fp32 -> Xt (TIN,B,N) bf16
// ---------------------------------------------------------------------------
__global__ __launch_bounds__(256) void transpose_X_bf(const float* __restrict__ X,
                                                      short* __restrict__ Xt) {
    int idx = blockIdx.x * 256 + threadIdx.x;   // t*(B*N) + b*N + n
    int n = idx & (N_IN - 1);
    int b = (idx >> 8) & (B - 1);
    int t = idx >> 14;
    Xt[idx] = (short)f2bf(X[(b * TIN + t) * N_IN + n]);
}

// ---------------------------------------------------------------------------
// Batched MFMA GEMM (large-parallelism path, encoder gi):
// C[r][c] = sum_k A[r][k]*W[c][k] + bias[c]; one 16x16 tile per wave.
// grid=(cols/16, rows/64), block=256.
// ---------------------------------------------------------------------------
__global__ __launch_bounds__(256) void mfma_gemm_bias(
    const short* __restrict__ A, int lda,
    const short* __restrict__ W, int ldw,
    const float* __restrict__ bias,
    float* __restrict__ C, int ldc, int K) {
    int wave = threadIdx.x >> 6;
    int lane = threadIdx.x & 63;
    int r0 = blockIdx.y * 64 + wave * 16;
    int c0 = blockIdx.x * 16;
    int lrow = lane & 15;
    int ko8 = (lane >> 4) * 8;
    const short* ap = A + (size_t)(r0 + lrow) * lda + ko8;
    const short* wp = W + (size_t)(c0 + lrow) * ldw + ko8;
    floatx4 acc = {0.f, 0.f, 0.f, 0.f};
    #pragma unroll 4
    for (int k = 0; k < K; k += 32) {
        bf16x8 a = *(const bf16x8*)(ap + k);
        bf16x8 b = *(const bf16x8*)(wp + k);
        acc = __builtin_amdgcn_mfma_f32_16x16x32_bf16(a, b, acc, 0, 0, 0);
    }
    int col = c0 + lrow;
    float bv = bias[col];
    int rbase = r0 + (lane >> 4) * 4;
    #pragma unroll
    for (int i = 0; i < 4; i++)
        C[(size_t)(rbase + i) * ldc + col] = acc[i] + bv;
}

// ---------------------------------------------------------------------------
// K-split MFMA GEMM: one 16x16 tile per BLOCK, 4 waves each take K/4,
// LDS reduction. For latency-bound small-M GEMMs (fc1, fc2).
// grid=(cols/16, rows/16), block=256. K % 128 == 0.
// ---------------------------------------------------------------------------
__global__ __launch_bounds__(256) void mfma_gemm_bias_ks(
    const short* __restrict__ A, int lda,
    const short* __restrict__ W, int ldw,
    const float* __restrict__ bias,
    float* __restrict__ C, int ldc, int K) {
    __shared__ float lds[4][64][4];
    int wave = threadIdx.x >> 6;
    int lane = threadIdx.x & 63;
    int r0 = blockIdx.y * 16;
    int c0 = blockIdx.x * 16;
    int Kq = K >> 2;
    int lrow = lane & 15;
    int ko8 = (lane >> 4) * 8;
    const short* ap = A + (size_t)(r0 + lrow) * lda + wave * Kq + ko8;
    const short* wp = W + (size_t)(c0 + lrow) * ldw + wave * Kq + ko8;
    floatx4 acc = {0.f, 0.f, 0.f, 0.f};
    #pragma unroll 4
    for (int k = 0; k < Kq; k += 32) {
        bf16x8 a = *(const bf16x8*)(ap + k);
        bf16x8 b = *(const bf16x8*)(wp + k);
        acc = __builtin_amdgcn_mfma_f32_16x16x32_bf16(a, b, acc, 0, 0, 0);
    }
    #pragma unroll
    for (int i = 0; i < 4; i++) lds[wave][lane][i] = acc[i];
    __syncthreads();
    int row = threadIdx.x >> 4, col = threadIdx.x & 15;
    int sl = (row >> 2) * 16 + col, rg = row & 3;
    float s = lds[0][sl][rg] + lds[1][sl][rg] + lds[2][sl][rg] + lds[3][sl][rg];
    C[(size_t)(r0 + row) * ldc + (c0 + col)] = s + bias[c0 + col];
}

// ---------------------------------------------------------------------------
// Encoder GRU step, fused + K-split: gh = h@Whh.T (3 gates) + pointwise.
// grid=(M/16, B/16), block=256 (4 waves x K/4 each), LDS reduce.
// h_f fp32 master state; bf16 mirror ping-ponged.
// ---------------------------------------------------------------------------
__global__ __launch_bounds__(256) void gru_step_enc(
    const short* __restrict__ h_in_bf, const short* __restrict__ Whh,
    const float* __restrict__ gi, const float* __restrict__ bhh,
    float* __restrict__ h_f, short* __restrict__ h_out_bf,
    short* __restrict__ seq_out_bf) {
    __shared__ float lr[4][64][4], lz[4][64][4], lnn[4][64][4];
    int wave = threadIdx.x >> 6;
    int lane = threadIdx.x & 63;
    int m0 = blockIdx.x * 16;
    int r0 = blockIdx.y * 16;
    int lrow = lane & 15;
    int ko8 = (lane >> 4) * 8;
    const int Kq = M >> 2;                       // 256
    const short* ap = h_in_bf + (size_t)(r0 + lrow) * M + wave * Kq + ko8;
    const short* wr = Whh + (size_t)(m0 + lrow) * M + wave * Kq + ko8;
    const short* wz = wr + (size_t)M * M;
    const short* wn = wr + (size_t)2 * M * M;
    floatx4 ar = {0.f, 0.f, 0.f, 0.f};
    floatx4 az = {0.f, 0.f, 0.f, 0.f};
    floatx4 ahn = {0.f, 0.f, 0.f, 0.f};
    #pragma unroll
    for (int k = 0; k < Kq; k += 32) {
        bf16x8 a = *(const bf16x8*)(ap + k);
        ar  = __builtin_amdgcn_mfma_f32_16x16x32_bf16(a, *(const bf16x8*)(wr + k), ar, 0, 0, 0);
        az  = __builtin_amdgcn_mfma_f32_16x16x32_bf16(a, *(const bf16x8*)(wz + k), az, 0, 0, 0);
        ahn = __builtin_amdgcn_mfma_f32_16x16x32_bf16(a, *(const bf16x8*)(wn + k), ahn, 0, 0, 0);
    }
    #pragma unroll
    for (int i = 0; i < 4; i++) {
        lr[wave][lane][i] = ar[i];
        lz[wave][lane][i] = az[i];
        lnn[wave][lane][i] = ahn[i];
    }
    __syncthreads();
    int row = threadIdx.x >> 4, col = threadIdx.x & 15;
    int sl = (row >> 2) * 16 + col, rg = row & 3;
    float sr = lr[0][sl][rg] + lr[1][sl][rg] + lr[2][sl][rg] + lr[3][sl][rg];
    float sz = lz[0][sl][rg] + lz[1][sl][rg] + lz[2][sl][rg] + lz[3][sl][rg];
    float sn = lnn[0][sl][rg] + lnn[1][sl][rg] + lnn[2][sl][rg] + lnn[3][sl][rg];
    int b = r0 + row, m = m0 + col;
    const float* gir = gi + (size_t)b * M3;
    float r = sigm(gir[m] + sr + bhh[m]);
    float z = sigm(gir[M + m] + sz + bhh[M + m]);
    float n = tanhf(gir[2 * M + m] + r * (sn + bhh[2 * M + m]));
    size_t hi = (size_t)b * M + m;
    float hv = (1.f - z) * n + z * h_f[hi];
    h_f[hi] = hv;
    short hb = (short)f2bf(hv);
    h_out_bf[hi] = hb;
    if (seq_out_bf) seq_out_bf[hi] = hb;
}

// ---------------------------------------------------------------------------
// Decoder GRU step, fused + K-split: gi = x@Wih.T, gh = h@Whh.T, pointwise.
// grid=(M/16, B/16), block=256. Kx % 128 == 0.
// ---------------------------------------------------------------------------
__global__ __launch_bounds__(256) void gru_step_dec(
    const short* __restrict__ x_bf, int Kx,
    const short* __restrict__ Wih,
    const short* __restrict__ h_in_bf, const short* __restrict__ Whh,
    const float* __restrict__ bih, const float* __restrict__ bhh,
    float* __restrict__ h_f, short* __restrict__ h_out_bf) {
    __shared__ float lr[4][64][4], lz[4][64][4], li[4][64][4], lh[4][64][4];
    int wave = threadIdx.x >> 6;
    int lane = threadIdx.x & 63;
    int m0 = blockIdx.x * 16;
    int r0 = blockIdx.y * 16;
    int lrow = lane & 15;
    int ko8 = (lane >> 4) * 8;
    floatx4 ar = {0.f, 0.f, 0.f, 0.f};
    floatx4 az = {0.f, 0.f, 0.f, 0.f};
    floatx4 ain = {0.f, 0.f, 0.f, 0.f};
    floatx4 ahn = {0.f, 0.f, 0.f, 0.f};
    {   // input-side quarter
        int Kq = Kx >> 2;
        const short* ap = x_bf + (size_t)(r0 + lrow) * Kx + wave * Kq + ko8;
        const short* wr = Wih + (size_t)(m0 + lrow) * Kx + wave * Kq + ko8;
        const short* wz = wr + (size_t)M * Kx;
        const short* wn = wr + (size_t)2 * M * Kx;
        #pragma unroll
        for (int k = 0; k < Kq; k += 32) {
            bf16x8 a = *(const bf16x8*)(ap + k);
            ar  = __builtin_amdgcn_mfma_f32_16x16x32_bf16(a, *(const bf16x8*)(wr + k), ar, 0, 0, 0);
            az  = __builtin_amdgcn_mfma_f32_16x16x32_bf16(a, *(const bf16x8*)(wz + k), az, 0, 0, 0);
            ain = __builtin_amdgcn_mfma_f32_16x16x32_bf16(a, *(const bf16x8*)(wn + k), ain, 0, 0, 0);
        }
    }
    {   // hidden-side quarter
        const int Kq = M >> 2;
        const short* ap = h_in_bf + (size_t)(r0 + lrow) * M + wave * Kq + ko8;
        const short* wr = Whh + (size_t)(m0 + lrow) * M + wave * Kq + ko8;
        const short* wz = wr + (size_t)M * M;
        const short* wn = wr + (size_t)2 * M * M;
        #pragma unroll
        for (int k = 0; k < Kq; k += 32) {
            bf16x8 a = *(const bf16x8*)(ap + k);
            ar  = __builtin_amdgcn_mfma_f32_16x16x32_bf16(a, *(const bf16x8*)(wr + k), ar, 0, 0, 0);
            az  = __builtin_amdgcn_mfma_f32_16x16x32_bf16(a, *(const bf16x8*)(wz + k), az, 0, 0, 0);
            ahn = __builtin_amdgcn_mfma_f32_16x16x32_bf16(a, *(const bf16x8*)(wn + k), ahn, 0, 0, 0);
        }
    }
    #pragma unroll
    for (int i = 0; i < 4; i++) {
        lr[wave][lane][i] = ar[i];
        lz[wave][lane][i] = az[i];
        li[wave][lane][i] = ain[i];
        lh[wave][lane][i] = ahn[i];
    }
    __syncthreads();
    int row = threadIdx.x >> 4, col = threadIdx.x & 15;
    int sl = (row >> 2) * 16 + col, rg = row & 3;
    float sr = lr[0][sl][rg] + lr[1][sl][rg] + lr[2][sl][rg] + lr[3][sl][rg];
    float sz = lz[0][sl][rg] + lz[1][sl][rg] + lz[2][sl][rg] + lz[3][sl][rg];
    float si = li[0][sl][rg] + li[1][sl][rg] + li[2][sl][rg] + li[3][sl][rg];
    float sh = lh[0][sl][rg] + lh[1][sl][rg] + lh[2][sl][rg] + lh[3][sl][rg];
    int b = r0 + row, m = m0 + col;
    float r = sigm(sr + bih[m] + bhh[m]);
    float z = sigm(sz + bih[M + m] + bhh[M + m]);
    float n = tanhf(si + bih[2 * M + m] + r * (sh + bhh[2 * M + m]));
    size_t hi = (size_t)b * M + m;
    float hv = (1.f - z) * n + z * h_f[hi];
    h_f[hi] = hv;
    h_out_bf[hi] = (short)f2bf(hv);
}

// ---------------------------------------------------------------------------
// LayerNorm + exact GELU over rows of length LM; reads fp32, writes bf16.
// ---------------------------------------------------------------------------
__global__ __launch_bounds__(256) void ln_gelu(const float* __restrict__ z,
                                               const float* __restrict__ g,
                                               const float* __restrict__ bt,
                                               short* __restrict__ zo) {
    __shared__ float red1[4], red2[4];
    int b = blockIdx.x, t = threadIdx.x;
    const float* row = z + (size_t)b * LM;
    float s = 0.f, ss = 0.f;
    for (int i = t; i < LM; i += 256) { float v = row[i]; s += v; ss += v * v; }
    #pragma unroll
    for (int off = 32; off > 0; off >>= 1) {
        s += __shfl_down(s, off, 64);
        ss += __shfl_down(ss, off, 64);
    }
    if ((t & 63) == 0) { red1[t >> 6] = s; red2[t >> 6] = ss; }
    __syncthreads();
    float S = red1[0] + red1[1] + red1[2] + red1[3];
    float SS = red2[0] + red2[1] + red2[2] + red2[3];
    float mu = S * (1.f / LM);
    float var = SS * (1.f / LM) - mu * mu;
    float inv = rsqrtf(var + 1e-5f);
    for (int i = t; i < LM; i += 256) {
        float v = (row[i] - mu) * inv * g[i] + bt[i];
        float gv = 0.5f * v * (1.f + erff(v * 0.70710678118654752f));
        zo[(size_t)b * LM + i] = (short)f2bf(gv);
    }
}

// ---------------------------------------------------------------------------
// Row softmax over O logits (fp32, stride ldl) -> y bf16 (compact B x O).
// ---------------------------------------------------------------------------
__global__ __launch_bounds__(256) void softmax_row(const float* __restrict__ logits,
                                                   int ldl, short* __restrict__ y) {
    __shared__ float redm[4], reds[4];
    int b = blockIdx.x, t = threadIdx.x;
    const float* row = logits + (size_t)b * ldl;
    float v0 = row[t], v1 = row[t + 256];
    float mx = fmaxf(v0, v1);
    #pragma unroll
    for (int off = 32; off > 0; off >>= 1) mx = fmaxf(mx, __shfl_down(mx, off, 64));
    if ((t & 63) == 0) redm[t >> 6] = mx;
    __syncthreads();
    mx = fmaxf(fmaxf(redm[0], redm[1]), fmaxf(redm[2], redm[3]));
    float e0 = expf(v0 - mx), e1 = expf(v1 - mx);
    float s = e0 + e1;
    #pragma unroll
    for (int off = 32; off > 0; off >>= 1) s += __shfl_down(s, off, 64);
    if ((t & 63) == 0) reds[t >> 6] = s;
    __syncthreads();
    s = reds[0] + reds[1] + reds[2] + reds[3];
    float inv = 1.f / s;
    y[b * O_DIM + t] = (short)f2bf(e0 * inv);
    y[b * O_DIM + t + 256] = (short)f2bf(e1 * inv);
}

extern "C" void kernel_launch(void* const* d_in, const int* in_sizes, int n_in,
                              void* d_out, int out_size, void* d_ws, size_t ws_size,
                              hipStream_t stream) {
    const float* X        = (const float*)d_in[0];
    const float* Y0       = (const float*)d_in[1];
    const float* enc_Wih0 = (const float*)d_in[2];
    const float* enc_Whh0 = (const float*)d_in[3];
    const float* enc_bih0 = (const float*)d_in[4];
    const float* enc_bhh0 = (const float*)d_in[5];
    const float* enc_Wih1 = (const float*)d_in[6];
    const float* enc_Whh1 = (const float*)d_in[7];
    const float* enc_bih1 = (const float*)d_in[8];
    const float* enc_bhh1 = (const float*)d_in[9];
    const float* dec_Wih0 = (const float*)d_in[10];
    const float* dec_Whh0 = (const float*)d_in[11];
    const float* dec_bih0 = (const float*)d_in[12];
    const float* dec_bhh0 = (const float*)d_in[13];
    const float* dec_Wih1 = (const float*)d_in[14];
    const float* dec_Whh1 = (const float*)d_in[15];
    const float* dec_bih1 = (const float*)d_in[16];
    const float* dec_bhh1 = (const float*)d_in[17];
    const float* fc1_w    = (const float*)d_in[18];
    const float* fc1_b    = (const float*)d_in[19];
    const float* ln_g     = (const float*)d_in[20];
    const float* ln_b     = (const float*)d_in[21];
    const float* fc2_w    = (const float*)d_in[22];
    const float* fc2_b    = (const float*)d_in[23];
    float* out = (float*)d_out;

    // ---- workspace carve-up ----
    char* p = (char*)d_ws;
    auto carve = [&](size_t bytes) {
        void* r = p;
        p += (bytes + 255) & ~(size_t)255;
        return r;
    };
    short* Xt    = (short*)carve((size_t)TIN * B * N_IN * 2);
    short* seqA  = (short*)carve((size_t)TIN * B * M * 2);
    float* gi_ch = (float*)carve((size_t)CH * B * M3 * 4);
    short* we_ih0 = (short*)carve((size_t)M3 * N_IN * 2);
    short* we_hh0 = (short*)carve((size_t)M3 * M * 2);
    short* we_ih1 = (short*)carve((size_t)M3 * M * 2);
    short* we_hh1 = (short*)carve((size_t)M3 * M * 2);
    short* wd_ih0 = (short*)carve((size_t)M3 * O_DIM * 2);
    short* wd_hh0 = (short*)carve((size_t)M3 * M * 2);
    short* wd_ih1 = (short*)carve((size_t)M3 * M * 2);
    short* wd_hh1 = (short*)carve((size_t)M3 * M * 2);
    short* wfc1   = (short*)carve((size_t)LM * M * 2);
    short* wfc2   = (short*)carve((size_t)O_DIM * LM * 2);
    float* h0f = (float*)carve((size_t)B * M * 4);
    float* h1f = (float*)carve((size_t)B * M * 4);
    short* h0b = (short*)carve((size_t)2 * B * M * 2);   // ping-pong
    short* h1b = (short*)carve((size_t)2 * B * M * 2);
    short* yb  = (short*)carve((size_t)B * O_DIM * 2);
    float* zb  = (float*)carve((size_t)B * LM * 4);
    short* zbb = (short*)carve((size_t)B * LM * 2);

    auto cast = [&](const float* src, short* dst, int n) {
        cast_bf<<<(n + 255) / 256, 256, 0, stream>>>(src, dst, n);
    };
    cast(enc_Wih0, we_ih0, M3 * N_IN);
    cast(enc_Whh0, we_hh0, M3 * M);
    cast(enc_Wih1, we_ih1, M3 * M);
    cast(enc_Whh1, we_hh1, M3 * M);
    cast(dec_Wih0, wd_ih0, M3 * O_DIM);
    cast(dec_Whh0, wd_hh0, M3 * M);
    cast(dec_Wih1, wd_ih1, M3 * M);
    cast(dec_Whh1, wd_hh1, M3 * M);
    cast(fc1_w, wfc1, LM * M);
    cast(fc2_w, wfc2, O_DIM * LM);
    cast(Y0, yb, B * O_DIM);
    transpose_X_bf<<<(TIN * B * N_IN) / 256, 256, 0, stream>>>(X, Xt);

    hipMemsetAsync(h0f, 0, (size_t)B * M * 4, stream);
    hipMemsetAsync(h1f, 0, (size_t)B * M * 4, stream);
    hipMemsetAsync(h0b, 0, (size_t)B * M * 2, stream);   // parity-0 buffer
    hipMemsetAsync(h1b, 0, (size_t)B * M * 2, stream);

    dim3 gruGrid(M / 16, B / 16);     // 64 x 4 = 256 blocks, 4 waves each

    // -------------------- encoder --------------------
    for (int layer = 0; layer < 2; layer++) {
        const short* Wih = layer ? we_ih1 : we_ih0;
        const short* Whh = layer ? we_hh1 : we_hh0;
        const float* bih = layer ? enc_bih1 : enc_bih0;
        const float* bhh = layer ? enc_bhh1 : enc_bhh0;
        const short* inseq = layer ? seqA : Xt;
        const int Kin = layer ? M : N_IN;
        float* hf = layer ? h1f : h0f;
        short* hb = layer ? h1b : h0b;
        for (int c = 0; c < TIN / CH; c++) {
            mfma_gemm_bias<<<dim3(M3 / 16, CH * B / 64), 256, 0, stream>>>(
                inseq + (size_t)c * CH * B * Kin, Kin, Wih, Kin, bih,
                gi_ch, M3, Kin);
            for (int tt = 0; tt < CH; tt++) {
                int t = c * CH + tt;
                int pin = t & 1, pout = pin ^ 1;
                short* so = (layer == 0) ? (seqA + (size_t)t * B * M) : nullptr;
                gru_step_enc<<<gruGrid, 256, 0, stream>>>(
                    hb + (size_t)pin * B * M, Whh,
                    gi_ch + (size_t)tt * B * M3, bhh,
                    hf, hb + (size_t)pout * B * M, so);
            }
        }
    }
    // after 128 steps the live bf16 state is at parity 0 for both layers.

    // -------------------- decoder --------------------
    for (int t = 0; t < TDEC; t++) {
        int pin = t & 1, pout = pin ^ 1;
        gru_step_dec<<<gruGrid, 256, 0, stream>>>(
            yb, O_DIM, wd_ih0,
            h0b + (size_t)pin * B * M, wd_hh0,
            dec_bih0, dec_bhh0, h0f, h0b + (size_t)pout * B * M);
        gru_step_dec<<<gruGrid, 256, 0, stream>>>(
            h0b + (size_t)pout * B * M, M, wd_ih1,
            h1b + (size_t)pin * B * M, wd_hh1,
            dec_bih1, dec_bhh1, h1f, h1b + (size_t)pout * B * M);
        mfma_gemm_bias_ks<<<dim3(LM / 16, B / 16), 256, 0, stream>>>(
            h1b + (size_t)pout * B * M, M, wfc1, M, fc1_b, zb, LM, M);
        ln_gelu<<<B, 256, 0, stream>>>(zb, ln_g, ln_b, zbb);
        mfma_gemm_bias_ks<<<dim3(O_DIM / 16, B / 16), 256, 0, stream>>>(
            zbb, LM, wfc2, LM, fc2_b, out + (size_t)t * O_DIM, TDEC * O_DIM, LM);
        softmax_row<<<B, 256, 0, stream>>>(out + (size_t)t * O_DIM,
                                           TDEC * O_DIM, yb);
    }
}